// Round 1
// baseline (2703.251 us; speedup 1.0000x reference)
//
#include <hip/hip_runtime.h>

// Problem constants (match reference)
constexpr int   NVEC  = 131072;   // N
constexpr int   DIMC  = 128;      // latent dim
constexpr int   KC    = 4096;     // codebook size
constexpr float DECAYC = 0.99f;
constexpr float OMDECAY = 0.01f;  // float(1.0 - 0.99) == 0.01f bit pattern
constexpr float EPSC  = 1e-5f;

// ---------------- kernel A: nhe2[k] = -0.5 * sum_d embed[d][k]^2 ----------------
__global__ __launch_bounds__(256) void colnorm_kernel(const float* __restrict__ embed,
                                                      float* __restrict__ nhe2) {
    int k = blockIdx.x * 256 + threadIdx.x;   // coalesced in k
    float acc = 0.f;
    for (int d = 0; d < DIMC; ++d) {
        float v = embed[(size_t)d * KC + k];
        acc = fmaf(v, v, acc);
    }
    nhe2[k] = -0.5f * acc;
}

// ---------------- kernel T: embedT[k][d] = embed[d][k] ----------------
__global__ __launch_bounds__(256) void transpose_kernel(const float* __restrict__ embed,
                                                        float* __restrict__ embedT) {
    int idx = blockIdx.x * 256 + threadIdx.x;  // over 524288
    int d = idx >> 12;         // / 4096
    int k = idx & (KC - 1);
    embedT[(size_t)k * DIMC + d] = embed[idx];
}

// ---------------- kernel B: fused fp32 GEMM + argmin ----------------
// Tile: 64 rows x 128 cols per block, 256 threads (16 tx x 16 ty), micro 4x8.
// Xs resident (full D), Es streamed in two 64-deep chunks. LDS = 66.5 KB -> 2 blocks/CU.
__global__ __launch_bounds__(256) void dist_argmin_kernel(
    const float* __restrict__ x, const float* __restrict__ embed,
    const float* __restrict__ nhe2, float* __restrict__ ind_f, int* __restrict__ ind_i)
{
    __shared__ float Xs[64][132];   // +4 pad: conflict-free broadcast a-reads
    __shared__ float Es[64][128];   // [k-chunk][col]

    const int tid = threadIdx.x;
    const int tx = tid & 15;
    const int ty = tid >> 4;
    const size_t rowBase = (size_t)blockIdx.x * 64;

    // Stage X tile: 64 rows x 128, 2048 float4, 8 per thread (coalesced)
    for (int i = 0; i < 8; ++i) {
        int f4 = tid + i * 256;
        int r  = f4 >> 5;
        int c  = (f4 & 31) << 2;
        float4 v = *reinterpret_cast<const float4*>(x + (rowBase + r) * DIMC + c);
        *reinterpret_cast<float4*>(&Xs[r][c]) = v;
    }

    float best[4];
    int   bidx[4];
#pragma unroll
    for (int i = 0; i < 4; ++i) { best[i] = -3.4e38f; bidx[i] = 0; }

    for (int ct = 0; ct < KC / 128; ++ct) {
        const int colBase = ct * 128;
        float acc0[4][4] = {};
        float acc1[4][4] = {};

        for (int ch = 0; ch < 2; ++ch) {
            __syncthreads();
            // Stage E chunk: d in [64*ch, 64*ch+64), 128 cols
            for (int i = 0; i < 8; ++i) {
                int f4 = tid + i * 256;
                int dd = f4 >> 5;
                int c  = (f4 & 31) << 2;
                float4 v = *reinterpret_cast<const float4*>(
                    embed + (size_t)(ch * 64 + dd) * KC + colBase + c);
                *reinterpret_cast<float4*>(&Es[dd][c]) = v;
            }
            __syncthreads();

#pragma unroll 4
            for (int kk4 = 0; kk4 < 16; ++kk4) {
                float a[4][4];
#pragma unroll
                for (int i = 0; i < 4; ++i) {
                    float4 t = *reinterpret_cast<const float4*>(
                        &Xs[ty * 4 + i][ch * 64 + kk4 * 4]);
                    a[i][0] = t.x; a[i][1] = t.y; a[i][2] = t.z; a[i][3] = t.w;
                }
                float b0[4][4], b1[4][4];
#pragma unroll
                for (int t = 0; t < 4; ++t) {
                    float4 u = *reinterpret_cast<const float4*>(&Es[kk4 * 4 + t][tx * 4]);
                    b0[t][0] = u.x; b0[t][1] = u.y; b0[t][2] = u.z; b0[t][3] = u.w;
                    float4 w = *reinterpret_cast<const float4*>(&Es[kk4 * 4 + t][64 + tx * 4]);
                    b1[t][0] = w.x; b1[t][1] = w.y; b1[t][2] = w.z; b1[t][3] = w.w;
                }
#pragma unroll
                for (int i = 0; i < 4; ++i)
#pragma unroll
                    for (int t = 0; t < 4; ++t)
#pragma unroll
                        for (int j = 0; j < 4; ++j) {
                            acc0[i][j] = fmaf(a[i][t], b0[t][j], acc0[i][j]);
                            acc1[i][j] = fmaf(a[i][t], b1[t][j], acc1[i][j]);
                        }
            }
        }

        // Epilogue: score = dot - 0.5*|e|^2 ; strict > keeps first (lowest) index
        float4 n0 = *reinterpret_cast<const float4*>(nhe2 + colBase + tx * 4);
        float4 n1 = *reinterpret_cast<const float4*>(nhe2 + colBase + 64 + tx * 4);
        float nh0[4] = {n0.x, n0.y, n0.z, n0.w};
        float nh1[4] = {n1.x, n1.y, n1.z, n1.w};
#pragma unroll
        for (int i = 0; i < 4; ++i) {
#pragma unroll
            for (int j = 0; j < 4; ++j) {
                float s0 = acc0[i][j] + nh0[j];
                if (s0 > best[i]) { best[i] = s0; bidx[i] = colBase + tx * 4 + j; }
            }
#pragma unroll
            for (int j = 0; j < 4; ++j) {
                float s1 = acc1[i][j] + nh1[j];
                if (s1 > best[i]) { best[i] = s1; bidx[i] = colBase + 64 + tx * 4 + j; }
            }
        }
    }

    // Reduce across the 16 tx lanes of each row group (tie -> lowest index)
#pragma unroll
    for (int off = 1; off < 16; off <<= 1) {
#pragma unroll
        for (int i = 0; i < 4; ++i) {
            float vo = __shfl_xor(best[i], off, 64);
            int   io = __shfl_xor(bidx[i], off, 64);
            if (vo > best[i] || (vo == best[i] && io < bidx[i])) { best[i] = vo; bidx[i] = io; }
        }
    }
    if (tx == 0) {
#pragma unroll
        for (int i = 0; i < 4; ++i) {
            size_t g = rowBase + (size_t)ty * 4 + i;
            ind_i[g] = bidx[i];
            ind_f[g] = (float)bidx[i];
        }
    }
}

// ---------------- kernel C: gather quantize + loss + scatter EMA stats ----------------
// 8 rows per block (32 lanes/row, float4 per lane)
__global__ __launch_bounds__(256) void gather_scatter_kernel(
    const float* __restrict__ x, const float* __restrict__ embedT,
    const int* __restrict__ ind, float* __restrict__ quant_out,
    float* __restrict__ ws_sum, float* __restrict__ ws_cnt, float* __restrict__ ws_loss)
{
    const int tid  = threadIdx.x;
    const int lane = tid & 31;
    const int rl   = tid >> 5;
    const size_t n = (size_t)blockIdx.x * 8 + rl;
    const int k = ind[n];

    float4 xv = *reinterpret_cast<const float4*>(x + n * DIMC + lane * 4);
    float4 ev = *reinterpret_cast<const float4*>(embedT + (size_t)k * DIMC + lane * 4);

    // straight-through: x + (q - x), matches reference rounding
    float4 q;
    q.x = xv.x + (ev.x - xv.x); q.y = xv.y + (ev.y - xv.y);
    q.z = xv.z + (ev.z - xv.z); q.w = xv.w + (ev.w - xv.w);
    *reinterpret_cast<float4*>(quant_out + n * DIMC + lane * 4) = q;

    float d0 = ev.x - xv.x, d1 = ev.y - xv.y, d2 = ev.z - xv.z, d3 = ev.w - xv.w;
    float ls = d0 * d0 + d1 * d1 + d2 * d2 + d3 * d3;

    // scatter x into embed_sum[d][k]
    atomicAdd(&ws_sum[(size_t)(lane * 4 + 0) * KC + k], xv.x);
    atomicAdd(&ws_sum[(size_t)(lane * 4 + 1) * KC + k], xv.y);
    atomicAdd(&ws_sum[(size_t)(lane * 4 + 2) * KC + k], xv.z);
    atomicAdd(&ws_sum[(size_t)(lane * 4 + 3) * KC + k], xv.w);
    if (lane == 0) atomicAdd(&ws_cnt[k], 1.0f);

    // block-reduce loss -> one atomic per block
#pragma unroll
    for (int off = 32; off >= 1; off >>= 1) ls += __shfl_down(ls, off, 64);
    __shared__ float red[4];
    if ((tid & 63) == 0) red[tid >> 6] = ls;
    __syncthreads();
    if (tid == 0) atomicAdd(ws_loss, red[0] + red[1] + red[2] + red[3]);
}

// ---------------- kernel D: cluster_size_new, n_small, loss, inverse norm ----------------
__global__ __launch_bounds__(1024) void finalize_kernel(
    const float* __restrict__ cs, const float* __restrict__ ws_cnt,
    const float* __restrict__ ws_loss,
    float* __restrict__ out_loss, float* __restrict__ out_nsmall,
    float* __restrict__ out_csn, float* __restrict__ ws_inv)
{
    const int tid = threadIdx.x;
    float csn_loc[4];
    float lsum = 0.f, lsmall = 0.f;
#pragma unroll
    for (int i = 0; i < 4; ++i) {
        int k = tid + i * 1024;
        float csn = cs[k] * DECAYC + OMDECAY * ws_cnt[k];
        out_csn[k] = csn;
        csn_loc[i] = csn;
        lsum += csn;
        lsmall += (csn < 1.f) ? 1.f : 0.f;
    }
#pragma unroll
    for (int off = 32; off >= 1; off >>= 1) {
        lsum   += __shfl_down(lsum, off, 64);
        lsmall += __shfl_down(lsmall, off, 64);
    }
    __shared__ float sh1[16], sh2[16];
    __shared__ float ntot_s;
    if ((tid & 63) == 0) { sh1[tid >> 6] = lsum; sh2[tid >> 6] = lsmall; }
    __syncthreads();
    if (tid == 0) {
        float tot = 0.f, sm = 0.f;
        for (int w = 0; w < 16; ++w) { tot += sh1[w]; sm += sh2[w]; }
        ntot_s = tot;
        out_nsmall[0] = sm;
        out_loss[0] = ws_loss[0] * (1.0f / ((float)NVEC * (float)DIMC));
    }
    __syncthreads();
    float ntot = ntot_s;
    float scale = (ntot + (float)KC * EPSC) / ntot;  // embed_new = ean * scale / (csn+eps)
#pragma unroll
    for (int i = 0; i < 4; ++i) {
        int k = tid + i * 1024;
        ws_inv[k] = scale / (csn_loc[i] + EPSC);
    }
}

// ---------------- kernel E: embed_avg_new and embed_new ----------------
__global__ __launch_bounds__(256) void ema_embed_kernel(
    const float* __restrict__ ea, const float* __restrict__ ws_sum,
    const float* __restrict__ ws_inv, float* __restrict__ out_embed_new,
    float* __restrict__ out_ean)
{
    size_t i4 = ((size_t)blockIdx.x * 256 + threadIdx.x) * 4;  // over 524288
    float4 a = *reinterpret_cast<const float4*>(ea + i4);
    float4 s = *reinterpret_cast<const float4*>(ws_sum + i4);
    int k = (int)(i4 & (KC - 1));
    float4 inv = *reinterpret_cast<const float4*>(ws_inv + k);
    float e0 = a.x * DECAYC + OMDECAY * s.x;
    float e1 = a.y * DECAYC + OMDECAY * s.y;
    float e2 = a.z * DECAYC + OMDECAY * s.z;
    float e3 = a.w * DECAYC + OMDECAY * s.w;
    // out buffers are at odd float offsets -> scalar stores (no 16B alignment)
    out_ean[i4 + 0] = e0; out_ean[i4 + 1] = e1; out_ean[i4 + 2] = e2; out_ean[i4 + 3] = e3;
    out_embed_new[i4 + 0] = e0 * inv.x;
    out_embed_new[i4 + 1] = e1 * inv.y;
    out_embed_new[i4 + 2] = e2 * inv.z;
    out_embed_new[i4 + 3] = e3 * inv.w;
}

extern "C" void kernel_launch(void* const* d_in, const int* in_sizes, int n_in,
                              void* d_out, int out_size, void* d_ws, size_t ws_size,
                              hipStream_t stream) {
    const float* x     = (const float*)d_in[0];   // [N, D]
    const float* embed = (const float*)d_in[1];   // [D, K]
    const float* cs    = (const float*)d_in[2];   // [K]
    const float* ea    = (const float*)d_in[3];   // [D, K]

    float* out  = (float*)d_out;
    float* out0 = out;                 // quantize_st   [N, D]      16777216
    float* out1 = out + 16777216;      // quant_loss    scalar
    float* out2 = out + 16777217;      // n_small       scalar
    float* out3 = out + 16777218;      // embed_ind     [N] (float)
    float* out4 = out + 16908290;      // embed_new     [D, K]
    float* out5 = out + 17432578;      // cluster_size_new [K]
    float* out6 = out + 17436674;      // embed_avg_new [D, K]

    float* ws      = (float*)d_ws;
    float* ws_sum  = ws;               // 524288 (zeroed)
    float* ws_cnt  = ws + 524288;      // 4096   (zeroed)
    float* ws_loss = ws + 528384;      // 1 (+3 pad, zeroed)
    float* ws_inv  = ws + 528388;      // 4096
    float* nhe2    = ws + 532484;      // 4096
    float* embedT  = ws + 536580;      // 524288
    int*   ws_ind  = (int*)(ws + 1060868);  // 131072

    hipMemsetAsync(ws_sum, 0, (size_t)528388 * sizeof(float), stream);

    hipLaunchKernelGGL(colnorm_kernel,   dim3(KC / 256), dim3(256), 0, stream, embed, nhe2);
    hipLaunchKernelGGL(transpose_kernel, dim3((DIMC * KC) / 256), dim3(256), 0, stream, embed, embedT);
    hipLaunchKernelGGL(dist_argmin_kernel, dim3(NVEC / 64), dim3(256), 0, stream,
                       x, embed, nhe2, out3, ws_ind);
    hipLaunchKernelGGL(gather_scatter_kernel, dim3(NVEC / 8), dim3(256), 0, stream,
                       x, embedT, ws_ind, out0, ws_sum, ws_cnt, ws_loss);
    hipLaunchKernelGGL(finalize_kernel, dim3(1), dim3(1024), 0, stream,
                       cs, ws_cnt, ws_loss, out1, out2, out5, ws_inv);
    hipLaunchKernelGGL(ema_embed_kernel, dim3((DIMC * KC) / 1024), dim3(256), 0, stream,
                       ea, ws_sum, ws_inv, out4, out6);
}

// Round 2
// 1998.691 us; speedup vs baseline: 1.3525x; 1.3525x over previous
//
#include <hip/hip_runtime.h>

// Problem constants (match reference)
constexpr int   NVEC  = 131072;   // N
constexpr int   DIMC  = 128;      // latent dim
constexpr int   KC    = 4096;     // codebook size
constexpr float DECAYC = 0.99f;
constexpr float OMDECAY = 0.01f;
constexpr float EPSC  = 1e-5f;
constexpr float MARGIN = 0.1f;    // >> worst-case split-bf16 score error (~0.02)

typedef __bf16 v8bf __attribute__((ext_vector_type(8)));
typedef float  v4f  __attribute__((ext_vector_type(4)));

// ---------------- kernel A: nhe2[k] = -0.5 * sum_d embed[d][k]^2 (exact fp32) ----------------
__global__ __launch_bounds__(256) void colnorm_kernel(const float* __restrict__ embed,
                                                      float* __restrict__ nhe2) {
    int k = blockIdx.x * 256 + threadIdx.x;
    float acc = 0.f;
    for (int d = 0; d < DIMC; ++d) {
        float v = embed[(size_t)d * KC + k];
        acc = fmaf(v, v, acc);
    }
    nhe2[k] = -0.5f * acc;
}

// ---------------- kernel T: embedT[k][d] = embed[d][k] (fp32, for gather) ----------------
__global__ __launch_bounds__(256) void transpose_kernel(const float* __restrict__ embed,
                                                        float* __restrict__ embedT) {
    int idx = blockIdx.x * 256 + threadIdx.x;  // over 524288
    int d = idx >> 12;
    int k = idx & (KC - 1);
    embedT[(size_t)k * DIMC + d] = embed[idx];
}

// ---------------- kernel S: split embed into bf16 hi/lo, transposed to [k][d] ----------------
__global__ __launch_bounds__(256) void split_e_kernel(const float* __restrict__ embed,
                                                      __bf16* __restrict__ ehT,
                                                      __bf16* __restrict__ elT) {
    __shared__ __bf16 sh_h[64 * 130];
    __shared__ __bf16 sh_l[64 * 130];
    const int tid = threadIdx.x;
    const int kbase = blockIdx.x * 64;
    for (int it = 0; it < 32; ++it) {
        int idx = it * 256 + tid;       // 0..8191
        int d = idx >> 6;               // 0..127
        int k = idx & 63;
        float v = embed[(size_t)d * KC + kbase + k];   // coalesced in k
        __bf16 h = (__bf16)v;
        __bf16 l = (__bf16)(v - (float)h);
        sh_h[k * 130 + d] = h;
        sh_l[k * 130 + d] = l;
    }
    __syncthreads();
    for (int it = 0; it < 32; ++it) {
        int idx = it * 256 + tid;
        int k = idx >> 7;               // 0..63
        int d = idx & 127;
        ehT[(size_t)(kbase + k) * DIMC + d] = sh_h[k * 130 + d];
        elT[(size_t)(kbase + k) * DIMC + d] = sh_l[k * 130 + d];
    }
}

// ---------------- kernel P1: MFMA split-bf16 GEMM + per-row top-2 tracking ----------------
// 256 thr = 4 waves; wave owns 32 rows (2 x 16-row tiles); A frags in registers.
// embed chunk (64 cols x 128 k, hi+lo) staged in LDS, stride 136 (pad 8) ->
// fragment ds_read_b128 banks perfectly balanced (8 words/bank).
__global__ __launch_bounds__(256) void phase1_kernel(
    const float* __restrict__ x, const __bf16* __restrict__ ehT,
    const __bf16* __restrict__ elT, const float* __restrict__ nhe2,
    float* __restrict__ out_indf, int* __restrict__ ws_ind, float* __restrict__ ws_gap)
{
    __shared__ __bf16 Eh[64 * 136];
    __shared__ __bf16 El[64 * 136];
    const int tid  = threadIdx.x;
    const int wave = tid >> 6;
    const int lane = tid & 63;
    const int c    = lane & 15;     // MFMA m / n index
    const int q    = lane >> 4;     // quad
    const int rowBase = blockIdx.x * 128 + wave * 32;

    // Build A fragments from fp32 x (split in-register; hi + exact residual lo)
    v8bf ah[2][4], al[2][4];
#pragma unroll
    for (int t = 0; t < 2; ++t)
#pragma unroll
        for (int s = 0; s < 4; ++s) {
            const float* p = x + (size_t)(rowBase + t * 16 + c) * DIMC + s * 32 + q * 8;
            float4 v0 = *reinterpret_cast<const float4*>(p);
            float4 v1 = *reinterpret_cast<const float4*>(p + 4);
            float vv[8] = {v0.x, v0.y, v0.z, v0.w, v1.x, v1.y, v1.z, v1.w};
            v8bf h, l;
#pragma unroll
            for (int j = 0; j < 8; ++j) {
                __bf16 hh = (__bf16)vv[j];
                h[j] = hh;
                l[j] = (__bf16)(vv[j] - (float)hh);
            }
            ah[t][s] = h; al[t][s] = l;
        }

    float b1[8], b2[8]; int i1[8];
#pragma unroll
    for (int s = 0; s < 8; ++s) { b1[s] = -3.4e38f; b2[s] = -3.4e38f; i1[s] = 0; }

    for (int chunk = 0; chunk < KC / 64; ++chunk) {
        const int colChunk = chunk * 64;
        // stage 64 cols x 128 k (hi+lo): 4 KB per instr, coalesced
#pragma unroll
        for (int it = 0; it < 4; ++it) {
            int f  = tid + it * 256;        // 0..1023
            int col = f >> 4;               // 0..63
            int kk  = (f & 15) * 8;         // 0..120
            *reinterpret_cast<v8bf*>(&Eh[col * 136 + kk]) =
                *reinterpret_cast<const v8bf*>(ehT + (size_t)(colChunk + col) * DIMC + kk);
            *reinterpret_cast<v8bf*>(&El[col * 136 + kk]) =
                *reinterpret_cast<const v8bf*>(elT + (size_t)(colChunk + col) * DIMC + kk);
        }
        __syncthreads();

#pragma unroll
        for (int ct = 0; ct < 4; ++ct) {
            const int colLocal = ct * 16 + c;
            const int colG = colChunk + colLocal;
            v8bf bh[4], bl[4];
#pragma unroll
            for (int s = 0; s < 4; ++s) {
                bh[s] = *reinterpret_cast<const v8bf*>(&Eh[colLocal * 136 + s * 32 + q * 8]);
                bl[s] = *reinterpret_cast<const v8bf*>(&El[colLocal * 136 + s * 32 + q * 8]);
            }
            v4f acc0 = {0.f, 0.f, 0.f, 0.f};
            v4f acc1 = {0.f, 0.f, 0.f, 0.f};
#pragma unroll
            for (int s = 0; s < 4; ++s) {
                acc0 = __builtin_amdgcn_mfma_f32_16x16x32_bf16(ah[0][s], bh[s], acc0, 0, 0, 0);
                acc1 = __builtin_amdgcn_mfma_f32_16x16x32_bf16(ah[1][s], bh[s], acc1, 0, 0, 0);
                acc0 = __builtin_amdgcn_mfma_f32_16x16x32_bf16(ah[0][s], bl[s], acc0, 0, 0, 0);
                acc1 = __builtin_amdgcn_mfma_f32_16x16x32_bf16(ah[1][s], bl[s], acc1, 0, 0, 0);
                acc0 = __builtin_amdgcn_mfma_f32_16x16x32_bf16(al[0][s], bh[s], acc0, 0, 0, 0);
                acc1 = __builtin_amdgcn_mfma_f32_16x16x32_bf16(al[1][s], bh[s], acc1, 0, 0, 0);
            }
            float nh = nhe2[colG];
#pragma unroll
            for (int r = 0; r < 4; ++r) {
                float s0 = acc0[r] + nh;
                if (s0 > b1[r])      { b2[r] = b1[r]; b1[r] = s0; i1[r] = colG; }
                else if (s0 > b2[r]) { b2[r] = s0; }
                float s1 = acc1[r] + nh;
                if (s1 > b1[4 + r])      { b2[4 + r] = b1[4 + r]; b1[4 + r] = s1; i1[4 + r] = colG; }
                else if (s1 > b2[4 + r]) { b2[4 + r] = s1; }
            }
        }
        __syncthreads();
    }

    // top-2 merge across the 16 col-lanes of each row group
#pragma unroll
    for (int off = 1; off < 16; off <<= 1) {
#pragma unroll
        for (int s = 0; s < 8; ++s) {
            float ob1 = __shfl_xor(b1[s], off, 64);
            int   oi1 = __shfl_xor(i1[s], off, 64);
            float ob2 = __shfl_xor(b2[s], off, 64);
            if (ob1 > b1[s] || (ob1 == b1[s] && oi1 < i1[s])) {
                b2[s] = fmaxf(b1[s], ob2); b1[s] = ob1; i1[s] = oi1;
            } else {
                b2[s] = fmaxf(b2[s], ob1);
            }
        }
    }
    if (c == 0) {
#pragma unroll
        for (int s = 0; s < 8; ++s) {
            int t = s >> 2, r = s & 3;
            int row = rowBase + t * 16 + q * 4 + r;
            ws_ind[row]   = i1[s];
            out_indf[row] = (float)i1[s];
            ws_gap[row]   = b1[s] - b2[s];
        }
    }
}

// ---------------- kernel F: compact flagged rows (gap < MARGIN) ----------------
__global__ __launch_bounds__(256) void flag_kernel(const float* __restrict__ ws_gap,
                                                   int* __restrict__ ws_nflag,
                                                   int* __restrict__ ws_list) {
    int n = blockIdx.x * 256 + threadIdx.x;
    if (ws_gap[n] < MARGIN) {
        int p = atomicAdd(ws_nflag, 1);
        ws_list[p] = n;
    }
}

// ---------------- kernel R: exact fp32 rescore of flagged rows (16 rows/block) ----------------
// Arithmetic (ascending-d fmaf chain + nhe2 add) is bit-identical to the round-1
// kernel that matched the numpy reference on all rows.
__global__ __launch_bounds__(256) void rescore_kernel(
    const float* __restrict__ x, const float* __restrict__ embed,
    const float* __restrict__ nhe2, const int* __restrict__ ws_list,
    const int* __restrict__ ws_nflag, int* __restrict__ ws_ind,
    float* __restrict__ out_indf)
{
    __shared__ float xs[128][16];
    __shared__ float redv[4][16];
    __shared__ int   redi[4][16];
    const int tid  = threadIdx.x;
    const int lane = tid & 63;
    const int wave = tid >> 6;
    const int nflag = *ws_nflag;

    for (int g = blockIdx.x; g * 16 < nflag; g += gridDim.x) {
        const int base = g * 16;
        const int cnt  = min(16, nflag - base);
        __syncthreads();   // protect xs/red from previous iteration
        for (int it = 0; it < 2; ++it) {
            int f4 = tid + it * 256;              // 0..511
            int r  = f4 >> 5;                     // 0..15
            int d4 = (f4 & 31) * 4;
            int row = ws_list[base + (r < cnt ? r : 0)];
            float4 v = *reinterpret_cast<const float4*>(x + (size_t)row * DIMC + d4);
            xs[d4 + 0][r] = v.x; xs[d4 + 1][r] = v.y;
            xs[d4 + 2][r] = v.z; xs[d4 + 3][r] = v.w;
        }
        __syncthreads();

        float b1[16]; int i1[16];
#pragma unroll
        for (int r = 0; r < 16; ++r) { b1[r] = -3.4e38f; i1[r] = 0; }

        for (int i = 0; i < 16; ++i) {
            int col = tid + i * 256;
            float acc[16];
#pragma unroll
            for (int r = 0; r < 16; ++r) acc[r] = 0.f;
            for (int d = 0; d < DIMC; ++d) {
                float ev = embed[(size_t)d * KC + col];
                float4 xa = *reinterpret_cast<const float4*>(&xs[d][0]);
                float4 xb = *reinterpret_cast<const float4*>(&xs[d][4]);
                float4 xc = *reinterpret_cast<const float4*>(&xs[d][8]);
                float4 xd = *reinterpret_cast<const float4*>(&xs[d][12]);
                acc[0]  = fmaf(xa.x, ev, acc[0]);  acc[1]  = fmaf(xa.y, ev, acc[1]);
                acc[2]  = fmaf(xa.z, ev, acc[2]);  acc[3]  = fmaf(xa.w, ev, acc[3]);
                acc[4]  = fmaf(xb.x, ev, acc[4]);  acc[5]  = fmaf(xb.y, ev, acc[5]);
                acc[6]  = fmaf(xb.z, ev, acc[6]);  acc[7]  = fmaf(xb.w, ev, acc[7]);
                acc[8]  = fmaf(xc.x, ev, acc[8]);  acc[9]  = fmaf(xc.y, ev, acc[9]);
                acc[10] = fmaf(xc.z, ev, acc[10]); acc[11] = fmaf(xc.w, ev, acc[11]);
                acc[12] = fmaf(xd.x, ev, acc[12]); acc[13] = fmaf(xd.y, ev, acc[13]);
                acc[14] = fmaf(xd.z, ev, acc[14]); acc[15] = fmaf(xd.w, ev, acc[15]);
            }
            float nh = nhe2[col];
#pragma unroll
            for (int r = 0; r < 16; ++r) {
                float s = acc[r] + nh;
                if (s > b1[r]) { b1[r] = s; i1[r] = col; }  // cols ascending per thread
            }
        }
        // wave-level argmax merge (tie -> lowest col)
#pragma unroll
        for (int off = 1; off < 64; off <<= 1)
#pragma unroll
            for (int r = 0; r < 16; ++r) {
                float ob = __shfl_xor(b1[r], off, 64);
                int   oi = __shfl_xor(i1[r], off, 64);
                if (ob > b1[r] || (ob == b1[r] && oi < i1[r])) { b1[r] = ob; i1[r] = oi; }
            }
        if (lane == 0)
#pragma unroll
            for (int r = 0; r < 16; ++r) { redv[wave][r] = b1[r]; redi[wave][r] = i1[r]; }
        __syncthreads();
        if (tid < cnt) {
            float bv = redv[0][tid]; int bi = redi[0][tid];
#pragma unroll
            for (int w = 1; w < 4; ++w) {
                float ov = redv[w][tid]; int oi = redi[w][tid];
                if (ov > bv || (ov == bv && oi < bi)) { bv = ov; bi = oi; }
            }
            int row = ws_list[base + tid];
            ws_ind[row]   = bi;
            out_indf[row] = (float)bi;
        }
    }
}

// ---------------- kernel C: gather quantize + loss + scatter EMA stats ----------------
__global__ __launch_bounds__(256) void gather_scatter_kernel(
    const float* __restrict__ x, const float* __restrict__ embedT,
    const int* __restrict__ ind, float* __restrict__ quant_out,
    float* __restrict__ ws_sum, float* __restrict__ ws_cnt, float* __restrict__ ws_loss)
{
    const int tid  = threadIdx.x;
    const int lane = tid & 31;
    const int rl   = tid >> 5;
    const size_t n = (size_t)blockIdx.x * 8 + rl;
    const int k = ind[n];

    float4 xv = *reinterpret_cast<const float4*>(x + n * DIMC + lane * 4);
    float4 ev = *reinterpret_cast<const float4*>(embedT + (size_t)k * DIMC + lane * 4);

    float4 q;
    q.x = xv.x + (ev.x - xv.x); q.y = xv.y + (ev.y - xv.y);
    q.z = xv.z + (ev.z - xv.z); q.w = xv.w + (ev.w - xv.w);
    *reinterpret_cast<float4*>(quant_out + n * DIMC + lane * 4) = q;

    float d0 = ev.x - xv.x, d1 = ev.y - xv.y, d2 = ev.z - xv.z, d3 = ev.w - xv.w;
    float ls = d0 * d0 + d1 * d1 + d2 * d2 + d3 * d3;

    atomicAdd(&ws_sum[(size_t)(lane * 4 + 0) * KC + k], xv.x);
    atomicAdd(&ws_sum[(size_t)(lane * 4 + 1) * KC + k], xv.y);
    atomicAdd(&ws_sum[(size_t)(lane * 4 + 2) * KC + k], xv.z);
    atomicAdd(&ws_sum[(size_t)(lane * 4 + 3) * KC + k], xv.w);
    if (lane == 0) atomicAdd(&ws_cnt[k], 1.0f);

#pragma unroll
    for (int off = 32; off >= 1; off >>= 1) ls += __shfl_down(ls, off, 64);
    __shared__ float red[4];
    if ((tid & 63) == 0) red[tid >> 6] = ls;
    __syncthreads();
    if (tid == 0) atomicAdd(ws_loss, red[0] + red[1] + red[2] + red[3]);
}

// ---------------- kernel D: cluster_size_new, n_small, loss, inverse norm ----------------
__global__ __launch_bounds__(1024) void finalize_kernel(
    const float* __restrict__ cs, const float* __restrict__ ws_cnt,
    const float* __restrict__ ws_loss,
    float* __restrict__ out_loss, float* __restrict__ out_nsmall,
    float* __restrict__ out_csn, float* __restrict__ ws_inv)
{
    const int tid = threadIdx.x;
    float csn_loc[4];
    float lsum = 0.f, lsmall = 0.f;
#pragma unroll
    for (int i = 0; i < 4; ++i) {
        int k = tid + i * 1024;
        float csn = cs[k] * DECAYC + OMDECAY * ws_cnt[k];
        out_csn[k] = csn;
        csn_loc[i] = csn;
        lsum += csn;
        lsmall += (csn < 1.f) ? 1.f : 0.f;
    }
#pragma unroll
    for (int off = 32; off >= 1; off >>= 1) {
        lsum   += __shfl_down(lsum, off, 64);
        lsmall += __shfl_down(lsmall, off, 64);
    }
    __shared__ float sh1[16], sh2[16];
    __shared__ float ntot_s;
    if ((tid & 63) == 0) { sh1[tid >> 6] = lsum; sh2[tid >> 6] = lsmall; }
    __syncthreads();
    if (tid == 0) {
        float tot = 0.f, sm = 0.f;
        for (int w = 0; w < 16; ++w) { tot += sh1[w]; sm += sh2[w]; }
        ntot_s = tot;
        out_nsmall[0] = sm;
        out_loss[0] = ws_loss[0] * (1.0f / ((float)NVEC * (float)DIMC));
    }
    __syncthreads();
    float ntot = ntot_s;
    float scale = (ntot + (float)KC * EPSC) / ntot;
#pragma unroll
    for (int i = 0; i < 4; ++i) {
        int k = tid + i * 1024;
        ws_inv[k] = scale / (csn_loc[i] + EPSC);
    }
}

// ---------------- kernel E: embed_avg_new and embed_new ----------------
__global__ __launch_bounds__(256) void ema_embed_kernel(
    const float* __restrict__ ea, const float* __restrict__ ws_sum,
    const float* __restrict__ ws_inv, float* __restrict__ out_embed_new,
    float* __restrict__ out_ean)
{
    size_t i4 = ((size_t)blockIdx.x * 256 + threadIdx.x) * 4;
    float4 a = *reinterpret_cast<const float4*>(ea + i4);
    float4 s = *reinterpret_cast<const float4*>(ws_sum + i4);
    int k = (int)(i4 & (KC - 1));
    float4 inv = *reinterpret_cast<const float4*>(ws_inv + k);
    float e0 = a.x * DECAYC + OMDECAY * s.x;
    float e1 = a.y * DECAYC + OMDECAY * s.y;
    float e2 = a.z * DECAYC + OMDECAY * s.z;
    float e3 = a.w * DECAYC + OMDECAY * s.w;
    out_ean[i4 + 0] = e0; out_ean[i4 + 1] = e1; out_ean[i4 + 2] = e2; out_ean[i4 + 3] = e3;
    out_embed_new[i4 + 0] = e0 * inv.x;
    out_embed_new[i4 + 1] = e1 * inv.y;
    out_embed_new[i4 + 2] = e2 * inv.z;
    out_embed_new[i4 + 3] = e3 * inv.w;
}

extern "C" void kernel_launch(void* const* d_in, const int* in_sizes, int n_in,
                              void* d_out, int out_size, void* d_ws, size_t ws_size,
                              hipStream_t stream) {
    const float* x     = (const float*)d_in[0];   // [N, D]
    const float* embed = (const float*)d_in[1];   // [D, K]
    const float* cs    = (const float*)d_in[2];   // [K]
    const float* ea    = (const float*)d_in[3];   // [D, K]

    float* out  = (float*)d_out;
    float* out0 = out;                 // quantize_st   [N, D]
    float* out1 = out + 16777216;      // quant_loss
    float* out2 = out + 16777217;      // n_small
    float* out3 = out + 16777218;      // embed_ind [N]
    float* out4 = out + 16908290;      // embed_new [D, K]
    float* out5 = out + 17432578;      // cluster_size_new [K]
    float* out6 = out + 17436674;      // embed_avg_new [D, K]

    // workspace layout (float units); total ~7.9 MB
    float* ws       = (float*)d_ws;
    float* ws_sum   = ws;                    // 524288 (zeroed)
    float* ws_cnt   = ws + 524288;           // 4096   (zeroed)
    float* ws_loss  = ws + 528384;           // 1      (zeroed)
    int*   ws_nflag = (int*)(ws + 528385);   // 1      (zeroed)
    float* ws_inv   = ws + 528388;           // 4096
    float* nhe2     = ws + 532484;           // 4096
    float* embedT   = ws + 536580;           // 524288
    int*   ws_ind   = (int*)(ws + 1060868);  // 131072
    float* ws_gap   = ws + 1191940;          // 131072
    int*   ws_list  = (int*)(ws + 1323012);  // 131072
    __bf16* ehT     = (__bf16*)(ws + 1454084); // 524288 bf16 (262144 slots)
    __bf16* elT     = (__bf16*)(ws + 1716228); // 524288 bf16 (262144 slots)

    hipMemsetAsync(ws_sum, 0, (size_t)528386 * sizeof(float), stream);

    hipLaunchKernelGGL(colnorm_kernel,   dim3(KC / 256), dim3(256), 0, stream, embed, nhe2);
    hipLaunchKernelGGL(transpose_kernel, dim3((DIMC * KC) / 256), dim3(256), 0, stream, embed, embedT);
    hipLaunchKernelGGL(split_e_kernel,   dim3(KC / 64), dim3(256), 0, stream, embed, ehT, elT);
    hipLaunchKernelGGL(phase1_kernel,    dim3(NVEC / 128), dim3(256), 0, stream,
                       x, ehT, elT, nhe2, out3, ws_ind, ws_gap);
    hipLaunchKernelGGL(flag_kernel,      dim3(NVEC / 256), dim3(256), 0, stream,
                       ws_gap, ws_nflag, ws_list);
    hipLaunchKernelGGL(rescore_kernel,   dim3(512), dim3(256), 0, stream,
                       x, embed, nhe2, ws_list, ws_nflag, ws_ind, out3);
    hipLaunchKernelGGL(gather_scatter_kernel, dim3(NVEC / 8), dim3(256), 0, stream,
                       x, embedT, ws_ind, out0, ws_sum, ws_cnt, ws_loss);
    hipLaunchKernelGGL(finalize_kernel, dim3(1), dim3(1024), 0, stream,
                       cs, ws_cnt, ws_loss, out1, out2, out5, ws_inv);
    hipLaunchKernelGGL(ema_embed_kernel, dim3((DIMC * KC) / 1024), dim3(256), 0, stream,
                       ea, ws_sum, ws_inv, out4, out6);
}

// Round 3
// 1736.502 us; speedup vs baseline: 1.5567x; 1.1510x over previous
//
#include <hip/hip_runtime.h>

// Problem constants (match reference)
constexpr int   NVEC  = 131072;   // N
constexpr int   DIMC  = 128;      // latent dim
constexpr int   KC    = 4096;     // codebook size
constexpr float DECAYC = 0.99f;
constexpr float OMDECAY = 0.01f;
constexpr float EPSC  = 1e-5f;
constexpr float MARGIN = 0.1f;    // >> worst-case split-bf16 score error (~0.02)

typedef __bf16 v8bf __attribute__((ext_vector_type(8)));
typedef float  v4f  __attribute__((ext_vector_type(4)));

// ---------------- kernel A: nhe2[k] = -0.5 * sum_d embed[d][k]^2 (exact fp32) ----------------
__global__ __launch_bounds__(256) void colnorm_kernel(const float* __restrict__ embed,
                                                      float* __restrict__ nhe2) {
    int k = blockIdx.x * 256 + threadIdx.x;
    float acc = 0.f;
    for (int d = 0; d < DIMC; ++d) {
        float v = embed[(size_t)d * KC + k];
        acc = fmaf(v, v, acc);
    }
    nhe2[k] = -0.5f * acc;
}

// ---------------- kernel T: embedT[k][d] = embed[d][k] (fp32) ----------------
__global__ __launch_bounds__(256) void transpose_kernel(const float* __restrict__ embed,
                                                        float* __restrict__ embedT) {
    int idx = blockIdx.x * 256 + threadIdx.x;  // over 524288
    int d = idx >> 12;
    int k = idx & (KC - 1);
    embedT[(size_t)k * DIMC + d] = embed[idx];
}

// ---------------- kernel S: split embed into bf16 hi/lo, transposed to [k][d] ----------------
__global__ __launch_bounds__(256) void split_e_kernel(const float* __restrict__ embed,
                                                      __bf16* __restrict__ ehT,
                                                      __bf16* __restrict__ elT) {
    __shared__ __bf16 sh_h[64 * 130];
    __shared__ __bf16 sh_l[64 * 130];
    const int tid = threadIdx.x;
    const int kbase = blockIdx.x * 64;
    for (int it = 0; it < 32; ++it) {
        int idx = it * 256 + tid;       // 0..8191
        int d = idx >> 6;               // 0..127
        int k = idx & 63;
        float v = embed[(size_t)d * KC + kbase + k];   // coalesced in k
        __bf16 h = (__bf16)v;
        __bf16 l = (__bf16)(v - (float)h);
        sh_h[k * 130 + d] = h;
        sh_l[k * 130 + d] = l;
    }
    __syncthreads();
    for (int it = 0; it < 32; ++it) {
        int idx = it * 256 + tid;
        int k = idx >> 7;               // 0..63
        int d = idx & 127;
        ehT[(size_t)(kbase + k) * DIMC + d] = sh_h[k * 130 + d];
        elT[(size_t)(kbase + k) * DIMC + d] = sh_l[k * 130 + d];
    }
}

// ---------------- kernel P1: MFMA split-bf16 GEMM + per-row top-2 tracking ----------------
__global__ __launch_bounds__(256) void phase1_kernel(
    const float* __restrict__ x, const __bf16* __restrict__ ehT,
    const __bf16* __restrict__ elT, const float* __restrict__ nhe2,
    float* __restrict__ out_indf, int* __restrict__ ws_ind, float* __restrict__ ws_gap)
{
    __shared__ __bf16 Eh[64 * 136];
    __shared__ __bf16 El[64 * 136];
    const int tid  = threadIdx.x;
    const int wave = tid >> 6;
    const int lane = tid & 63;
    const int c    = lane & 15;     // MFMA m / n index
    const int q    = lane >> 4;     // quad
    const int rowBase = blockIdx.x * 128 + wave * 32;

    // Build A fragments from fp32 x (split in-register; hi + exact residual lo)
    v8bf ah[2][4], al[2][4];
#pragma unroll
    for (int t = 0; t < 2; ++t)
#pragma unroll
        for (int s = 0; s < 4; ++s) {
            const float* p = x + (size_t)(rowBase + t * 16 + c) * DIMC + s * 32 + q * 8;
            float4 v0 = *reinterpret_cast<const float4*>(p);
            float4 v1 = *reinterpret_cast<const float4*>(p + 4);
            float vv[8] = {v0.x, v0.y, v0.z, v0.w, v1.x, v1.y, v1.z, v1.w};
            v8bf h, l;
#pragma unroll
            for (int j = 0; j < 8; ++j) {
                __bf16 hh = (__bf16)vv[j];
                h[j] = hh;
                l[j] = (__bf16)(vv[j] - (float)hh);
            }
            ah[t][s] = h; al[t][s] = l;
        }

    float b1[8], b2[8]; int i1[8];
#pragma unroll
    for (int s = 0; s < 8; ++s) { b1[s] = -3.4e38f; b2[s] = -3.4e38f; i1[s] = 0; }

    for (int chunk = 0; chunk < KC / 64; ++chunk) {
        const int colChunk = chunk * 64;
#pragma unroll
        for (int it = 0; it < 4; ++it) {
            int f  = tid + it * 256;        // 0..1023
            int col = f >> 4;               // 0..63
            int kk  = (f & 15) * 8;         // 0..120
            *reinterpret_cast<v8bf*>(&Eh[col * 136 + kk]) =
                *reinterpret_cast<const v8bf*>(ehT + (size_t)(colChunk + col) * DIMC + kk);
            *reinterpret_cast<v8bf*>(&El[col * 136 + kk]) =
                *reinterpret_cast<const v8bf*>(elT + (size_t)(colChunk + col) * DIMC + kk);
        }
        __syncthreads();

#pragma unroll
        for (int ct = 0; ct < 4; ++ct) {
            const int colLocal = ct * 16 + c;
            const int colG = colChunk + colLocal;
            v8bf bh[4], bl[4];
#pragma unroll
            for (int s = 0; s < 4; ++s) {
                bh[s] = *reinterpret_cast<const v8bf*>(&Eh[colLocal * 136 + s * 32 + q * 8]);
                bl[s] = *reinterpret_cast<const v8bf*>(&El[colLocal * 136 + s * 32 + q * 8]);
            }
            v4f acc0 = {0.f, 0.f, 0.f, 0.f};
            v4f acc1 = {0.f, 0.f, 0.f, 0.f};
#pragma unroll
            for (int s = 0; s < 4; ++s) {
                acc0 = __builtin_amdgcn_mfma_f32_16x16x32_bf16(ah[0][s], bh[s], acc0, 0, 0, 0);
                acc1 = __builtin_amdgcn_mfma_f32_16x16x32_bf16(ah[1][s], bh[s], acc1, 0, 0, 0);
                acc0 = __builtin_amdgcn_mfma_f32_16x16x32_bf16(ah[0][s], bl[s], acc0, 0, 0, 0);
                acc1 = __builtin_amdgcn_mfma_f32_16x16x32_bf16(ah[1][s], bl[s], acc1, 0, 0, 0);
                acc0 = __builtin_amdgcn_mfma_f32_16x16x32_bf16(al[0][s], bh[s], acc0, 0, 0, 0);
                acc1 = __builtin_amdgcn_mfma_f32_16x16x32_bf16(al[1][s], bh[s], acc1, 0, 0, 0);
            }
            float nh = nhe2[colG];
#pragma unroll
            for (int r = 0; r < 4; ++r) {
                float s0 = acc0[r] + nh;
                if (s0 > b1[r])      { b2[r] = b1[r]; b1[r] = s0; i1[r] = colG; }
                else if (s0 > b2[r]) { b2[r] = s0; }
                float s1 = acc1[r] + nh;
                if (s1 > b1[4 + r])      { b2[4 + r] = b1[4 + r]; b1[4 + r] = s1; i1[4 + r] = colG; }
                else if (s1 > b2[4 + r]) { b2[4 + r] = s1; }
            }
        }
        __syncthreads();
    }

#pragma unroll
    for (int off = 1; off < 16; off <<= 1) {
#pragma unroll
        for (int s = 0; s < 8; ++s) {
            float ob1 = __shfl_xor(b1[s], off, 64);
            int   oi1 = __shfl_xor(i1[s], off, 64);
            float ob2 = __shfl_xor(b2[s], off, 64);
            if (ob1 > b1[s] || (ob1 == b1[s] && oi1 < i1[s])) {
                b2[s] = fmaxf(b1[s], ob2); b1[s] = ob1; i1[s] = oi1;
            } else {
                b2[s] = fmaxf(b2[s], ob1);
            }
        }
    }
    if (c == 0) {
#pragma unroll
        for (int s = 0; s < 8; ++s) {
            int t = s >> 2, r = s & 3;
            int row = rowBase + t * 16 + q * 4 + r;
            ws_ind[row]   = i1[s];
            out_indf[row] = (float)i1[s];
            ws_gap[row]   = b1[s] - b2[s];
        }
    }
}

// ---------------- kernel F: compact flagged rows (gap < MARGIN) ----------------
__global__ __launch_bounds__(256) void flag_kernel(const float* __restrict__ ws_gap,
                                                   int* __restrict__ ws_nflag,
                                                   int* __restrict__ ws_list) {
    int n = blockIdx.x * 256 + threadIdx.x;
    if (ws_gap[n] < MARGIN) {
        int p = atomicAdd(ws_nflag, 1);
        ws_list[p] = n;
    }
}

// ---------------- kernel R: exact fp32 rescore of flagged rows (16 rows/block) ----------------
__global__ __launch_bounds__(256) void rescore_kernel(
    const float* __restrict__ x, const float* __restrict__ embed,
    const float* __restrict__ nhe2, const int* __restrict__ ws_list,
    const int* __restrict__ ws_nflag, int* __restrict__ ws_ind,
    float* __restrict__ out_indf)
{
    __shared__ float xs[128][16];
    __shared__ float redv[4][16];
    __shared__ int   redi[4][16];
    const int tid  = threadIdx.x;
    const int lane = tid & 63;
    const int wave = tid >> 6;
    const int nflag = *ws_nflag;

    for (int g = blockIdx.x; g * 16 < nflag; g += gridDim.x) {
        const int base = g * 16;
        const int cnt  = min(16, nflag - base);
        __syncthreads();
        for (int it = 0; it < 2; ++it) {
            int f4 = tid + it * 256;
            int r  = f4 >> 5;
            int d4 = (f4 & 31) * 4;
            int row = ws_list[base + (r < cnt ? r : 0)];
            float4 v = *reinterpret_cast<const float4*>(x + (size_t)row * DIMC + d4);
            xs[d4 + 0][r] = v.x; xs[d4 + 1][r] = v.y;
            xs[d4 + 2][r] = v.z; xs[d4 + 3][r] = v.w;
        }
        __syncthreads();

        float b1[16]; int i1[16];
#pragma unroll
        for (int r = 0; r < 16; ++r) { b1[r] = -3.4e38f; i1[r] = 0; }

        for (int i = 0; i < 16; ++i) {
            int col = tid + i * 256;
            float acc[16];
#pragma unroll
            for (int r = 0; r < 16; ++r) acc[r] = 0.f;
            for (int d = 0; d < DIMC; ++d) {
                float ev = embed[(size_t)d * KC + col];
                float4 xa = *reinterpret_cast<const float4*>(&xs[d][0]);
                float4 xb = *reinterpret_cast<const float4*>(&xs[d][4]);
                float4 xc = *reinterpret_cast<const float4*>(&xs[d][8]);
                float4 xd = *reinterpret_cast<const float4*>(&xs[d][12]);
                acc[0]  = fmaf(xa.x, ev, acc[0]);  acc[1]  = fmaf(xa.y, ev, acc[1]);
                acc[2]  = fmaf(xa.z, ev, acc[2]);  acc[3]  = fmaf(xa.w, ev, acc[3]);
                acc[4]  = fmaf(xb.x, ev, acc[4]);  acc[5]  = fmaf(xb.y, ev, acc[5]);
                acc[6]  = fmaf(xb.z, ev, acc[6]);  acc[7]  = fmaf(xb.w, ev, acc[7]);
                acc[8]  = fmaf(xc.x, ev, acc[8]);  acc[9]  = fmaf(xc.y, ev, acc[9]);
                acc[10] = fmaf(xc.z, ev, acc[10]); acc[11] = fmaf(xc.w, ev, acc[11]);
                acc[12] = fmaf(xd.x, ev, acc[12]); acc[13] = fmaf(xd.y, ev, acc[13]);
                acc[14] = fmaf(xd.z, ev, acc[14]); acc[15] = fmaf(xd.w, ev, acc[15]);
            }
            float nh = nhe2[col];
#pragma unroll
            for (int r = 0; r < 16; ++r) {
                float s = acc[r] + nh;
                if (s > b1[r]) { b1[r] = s; i1[r] = col; }
            }
        }
#pragma unroll
        for (int off = 1; off < 64; off <<= 1)
#pragma unroll
            for (int r = 0; r < 16; ++r) {
                float ob = __shfl_xor(b1[r], off, 64);
                int   oi = __shfl_xor(i1[r], off, 64);
                if (ob > b1[r] || (ob == b1[r] && oi < i1[r])) { b1[r] = ob; i1[r] = oi; }
            }
        if (lane == 0)
#pragma unroll
            for (int r = 0; r < 16; ++r) { redv[wave][r] = b1[r]; redi[wave][r] = i1[r]; }
        __syncthreads();
        if (tid < cnt) {
            float bv = redv[0][tid]; int bi = redi[0][tid];
#pragma unroll
            for (int w = 1; w < 4; ++w) {
                float ov = redv[w][tid]; int oi = redi[w][tid];
                if (ov > bv || (ov == bv && oi < bi)) { bv = ov; bi = oi; }
            }
            int row = ws_list[base + tid];
            ws_ind[row]   = bi;
            out_indf[row] = (float)bi;
        }
    }
}

// ---------------- kernel H: histogram of cluster ids (int atomics) ----------------
__global__ __launch_bounds__(256) void hist_kernel(const int* __restrict__ ind,
                                                   int* __restrict__ cnt) {
    int n = blockIdx.x * 256 + threadIdx.x;
    atomicAdd(&cnt[ind[n]], 1);
}

// ---------------- kernel X: exclusive prefix sum over 4096 counts ----------------
__global__ __launch_bounds__(1024) void scan_kernel(const int* __restrict__ cnt,
                                                    int* __restrict__ start,
                                                    int* __restrict__ cursor) {
    __shared__ int sh[1024];
    const int t = threadIdx.x;
    int4 c = *reinterpret_cast<const int4*>(cnt + t * 4);
    int s = c.x + c.y + c.z + c.w;
    sh[t] = s;
    __syncthreads();
    for (int off = 1; off < 1024; off <<= 1) {
        int v = (t >= off) ? sh[t - off] : 0;
        __syncthreads();
        sh[t] += v;
        __syncthreads();
    }
    int s0 = (t == 0) ? 0 : sh[t - 1];
    start[t * 4 + 0] = s0; cursor[t * 4 + 0] = s0; s0 += c.x;
    start[t * 4 + 1] = s0; cursor[t * 4 + 1] = s0; s0 += c.y;
    start[t * 4 + 2] = s0; cursor[t * 4 + 2] = s0; s0 += c.z;
    start[t * 4 + 3] = s0; cursor[t * 4 + 3] = s0;
}

// ---------------- kernel B: scatter row ids into cluster-sorted order ----------------
__global__ __launch_bounds__(256) void bucket_kernel(const int* __restrict__ ind,
                                                     int* __restrict__ cursor,
                                                     int* __restrict__ sorted) {
    int n = blockIdx.x * 256 + threadIdx.x;
    int p = atomicAdd(&cursor[ind[n]], 1);
    sorted[p] = n;
}

// ---------------- kernel CS: per-cluster segmented sum + fused quantize + loss ----------------
// One block per cluster, 128 threads = one lane per d. Zero float atomics.
__global__ __launch_bounds__(128) void cluster_sum_kernel(
    const float* __restrict__ x, const float* __restrict__ embedT,
    const int* __restrict__ sorted, const int* __restrict__ start,
    const int* __restrict__ cnt, float* __restrict__ quant_out,
    float* __restrict__ ws_sum, float* __restrict__ ws_lpart)
{
    const int k = blockIdx.x;
    const int d = threadIdx.x;
    const int s0 = start[k];
    const int c  = cnt[k];
    const float e = embedT[(size_t)k * DIMC + d];
    float acc = 0.f, loss = 0.f;

    int row = (c > 0) ? sorted[s0] : 0;
    for (int i = 0; i < c; ++i) {
        int nrow = (i + 1 < c) ? sorted[s0 + i + 1] : 0;   // prefetch next row id
        float xv = x[(size_t)row * DIMC + d];
        float diff = e - xv;
        acc  += xv;
        loss = fmaf(diff, diff, loss);
        quant_out[(size_t)row * DIMC + d] = xv + diff;     // x + (q - x), matches ref rounding
        row = nrow;
    }
    ws_sum[(size_t)d * KC + k] = acc;

#pragma unroll
    for (int off = 32; off >= 1; off >>= 1) loss += __shfl_down(loss, off, 64);
    __shared__ float red[2];
    if ((d & 63) == 0) red[d >> 6] = loss;
    __syncthreads();
    if (d == 0) ws_lpart[k] = red[0] + red[1];
}

// ---------------- kernel D: cluster_size_new, n_small, loss, inverse norm ----------------
__global__ __launch_bounds__(1024) void finalize_kernel(
    const float* __restrict__ cs, const int* __restrict__ cnt,
    const float* __restrict__ ws_lpart,
    float* __restrict__ out_loss, float* __restrict__ out_nsmall,
    float* __restrict__ out_csn, float* __restrict__ ws_inv)
{
    const int tid = threadIdx.x;
    float csn_loc[4];
    float lsum = 0.f, lsmall = 0.f, lloss = 0.f;
#pragma unroll
    for (int i = 0; i < 4; ++i) {
        int k = tid + i * 1024;
        float csn = cs[k] * DECAYC + OMDECAY * (float)cnt[k];
        out_csn[k] = csn;
        csn_loc[i] = csn;
        lsum += csn;
        lsmall += (csn < 1.f) ? 1.f : 0.f;
        lloss += ws_lpart[k];
    }
#pragma unroll
    for (int off = 32; off >= 1; off >>= 1) {
        lsum   += __shfl_down(lsum, off, 64);
        lsmall += __shfl_down(lsmall, off, 64);
        lloss  += __shfl_down(lloss, off, 64);
    }
    __shared__ float sh1[16], sh2[16], sh3[16];
    __shared__ float ntot_s;
    if ((tid & 63) == 0) { sh1[tid >> 6] = lsum; sh2[tid >> 6] = lsmall; sh3[tid >> 6] = lloss; }
    __syncthreads();
    if (tid == 0) {
        float tot = 0.f, sm = 0.f, lo = 0.f;
        for (int w = 0; w < 16; ++w) { tot += sh1[w]; sm += sh2[w]; lo += sh3[w]; }
        ntot_s = tot;
        out_nsmall[0] = sm;
        out_loss[0] = lo * (1.0f / ((float)NVEC * (float)DIMC));
    }
    __syncthreads();
    float ntot = ntot_s;
    float scale = (ntot + (float)KC * EPSC) / ntot;
#pragma unroll
    for (int i = 0; i < 4; ++i) {
        int k = tid + i * 1024;
        ws_inv[k] = scale / (csn_loc[i] + EPSC);
    }
}

// ---------------- kernel E: embed_avg_new and embed_new ----------------
__global__ __launch_bounds__(256) void ema_embed_kernel(
    const float* __restrict__ ea, const float* __restrict__ ws_sum,
    const float* __restrict__ ws_inv, float* __restrict__ out_embed_new,
    float* __restrict__ out_ean)
{
    size_t i4 = ((size_t)blockIdx.x * 256 + threadIdx.x) * 4;
    float4 a = *reinterpret_cast<const float4*>(ea + i4);
    float4 s = *reinterpret_cast<const float4*>(ws_sum + i4);
    int k = (int)(i4 & (KC - 1));
    float4 inv = *reinterpret_cast<const float4*>(ws_inv + k);
    float e0 = a.x * DECAYC + OMDECAY * s.x;
    float e1 = a.y * DECAYC + OMDECAY * s.y;
    float e2 = a.z * DECAYC + OMDECAY * s.z;
    float e3 = a.w * DECAYC + OMDECAY * s.w;
    out_ean[i4 + 0] = e0; out_ean[i4 + 1] = e1; out_ean[i4 + 2] = e2; out_ean[i4 + 3] = e3;
    out_embed_new[i4 + 0] = e0 * inv.x;
    out_embed_new[i4 + 1] = e1 * inv.y;
    out_embed_new[i4 + 2] = e2 * inv.z;
    out_embed_new[i4 + 3] = e3 * inv.w;
}

extern "C" void kernel_launch(void* const* d_in, const int* in_sizes, int n_in,
                              void* d_out, int out_size, void* d_ws, size_t ws_size,
                              hipStream_t stream) {
    const float* x     = (const float*)d_in[0];   // [N, D]
    const float* embed = (const float*)d_in[1];   // [D, K]
    const float* cs    = (const float*)d_in[2];   // [K]
    const float* ea    = (const float*)d_in[3];   // [D, K]

    float* out  = (float*)d_out;
    float* out0 = out;                 // quantize_st   [N, D]
    float* out1 = out + 16777216;      // quant_loss
    float* out2 = out + 16777217;      // n_small
    float* out3 = out + 16777218;      // embed_ind [N]
    float* out4 = out + 16908290;      // embed_new [D, K]
    float* out5 = out + 17432578;      // cluster_size_new [K]
    float* out6 = out + 17436674;      // embed_avg_new [D, K]

    // workspace layout (float units) — peak footprint matches round-1 (~7.9 MB)
    float* ws       = (float*)d_ws;
    float* ws_sum   = ws;                    // 524288
    int*   ws_nflag = (int*)(ws + 528385);   // 1 (zeroed)
    float* ws_inv   = ws + 528388;           // 4096
    float* nhe2     = ws + 532484;           // 4096
    float* embedT   = ws + 536580;           // 524288
    int*   ws_ind   = (int*)(ws + 1060868);  // 131072
    float* ws_gap   = ws + 1191940;          // 131072
    int*   ws_list  = (int*)(ws + 1323012);  // 131072
    __bf16* ehT     = (__bf16*)(ws + 1454084); // 262144 floats of bf16 x2
    __bf16* elT     = (__bf16*)(ws + 1716228); // 262144 floats of bf16 x2
    // aliases (used only AFTER phase1 is done with ehT/elT):
    int*   ws_sorted = (int*)(ws + 1454084);   // 131072 ints, aliases ehT region
    int*   ws_cnt_i  = (int*)(ws + 1716228);   // 4096 ints,  aliases elT region
    int*   ws_start  = (int*)(ws + 1720324);   // 4096
    int*   ws_cursor = (int*)(ws + 1724420);   // 4096
    float* ws_lpart  = ws + 1728516;           // 4096

    hipMemsetAsync(ws_nflag, 0, sizeof(int), stream);

    hipLaunchKernelGGL(colnorm_kernel,   dim3(KC / 256), dim3(256), 0, stream, embed, nhe2);
    hipLaunchKernelGGL(transpose_kernel, dim3((DIMC * KC) / 256), dim3(256), 0, stream, embed, embedT);
    hipLaunchKernelGGL(split_e_kernel,   dim3(KC / 64), dim3(256), 0, stream, embed, ehT, elT);
    hipLaunchKernelGGL(phase1_kernel,    dim3(NVEC / 128), dim3(256), 0, stream,
                       x, ehT, elT, nhe2, out3, ws_ind, ws_gap);
    hipLaunchKernelGGL(flag_kernel,      dim3(NVEC / 256), dim3(256), 0, stream,
                       ws_gap, ws_nflag, ws_list);
    hipLaunchKernelGGL(rescore_kernel,   dim3(512), dim3(256), 0, stream,
                       x, embed, nhe2, ws_list, ws_nflag, ws_ind, out3);

    // counting sort by cluster id (aliases are safe: ehT/elT dead after phase1)
    hipMemsetAsync(ws_cnt_i, 0, KC * sizeof(int), stream);
    hipLaunchKernelGGL(hist_kernel,   dim3(NVEC / 256), dim3(256), 0, stream, ws_ind, ws_cnt_i);
    hipLaunchKernelGGL(scan_kernel,   dim3(1), dim3(1024), 0, stream, ws_cnt_i, ws_start, ws_cursor);
    hipLaunchKernelGGL(bucket_kernel, dim3(NVEC / 256), dim3(256), 0, stream,
                       ws_ind, ws_cursor, ws_sorted);
    hipLaunchKernelGGL(cluster_sum_kernel, dim3(KC), dim3(128), 0, stream,
                       x, embedT, ws_sorted, ws_start, ws_cnt_i, out0, ws_sum, ws_lpart);

    hipLaunchKernelGGL(finalize_kernel, dim3(1), dim3(1024), 0, stream,
                       cs, ws_cnt_i, ws_lpart, out1, out2, out5, ws_inv);
    hipLaunchKernelGGL(ema_embed_kernel, dim3((DIMC * KC) / 1024), dim3(256), 0, stream,
                       ea, ws_sum, ws_inv, out4, out6);
}